// Round 1
// baseline (368.897 us; speedup 1.0000x reference)
//
#include <hip/hip_runtime.h>
#include <stdint.h>

typedef _Float16 half8 __attribute__((ext_vector_type(8)));
typedef float    f32x4 __attribute__((ext_vector_type(4)));

static __device__ __forceinline__ void async_cp16(const void* g, void* l) {
  __builtin_amdgcn_global_load_lds(
      (const __attribute__((address_space(1))) uint32_t*)g,
      (__attribute__((address_space(3))) uint32_t*)l,
      16, 0, 0);
}

// ---------------------------------------------------------------------------
// Weight packing: MFMA-fragment order.
// packed idx = ((((nc*KCH + kc)*KSC + ks_in)*NTC + nt_in)*64 + lane)*8 + e
// logical:  n = (nc*NTC + nt_in)*16 + (lane&15)
//           k = (kc*KSC + ks_in)*32 + (lane>>4)*8 + e
// ---------------------------------------------------------------------------

static __device__ __forceinline__ void pack_one(
    const float* __restrict__ w, _Float16* __restrict__ dst, int idx,
    int N_src, int K, int NTC, int KSC, int KCH)
{
  const int e    = idx & 7;
  const int lane = (idx >> 3) & 63;
  int t = idx >> 9;
  const int nt_in = t % NTC; t /= NTC;
  const int ks_in = t % KSC; t /= KSC;
  const int kc    = t % KCH; t /= KCH;
  const int nc    = t;
  const int n = (nc * NTC + nt_in) * 16 + (lane & 15);
  const int k = (kc * KSC + ks_in) * 32 + ((lane >> 4) << 3) + e;
  const float val = (n < N_src) ? w[(size_t)n * K + k] : 0.0f;
  dst[idx] = (_Float16)val;
}

__global__ void pack_all(const float* __restrict__ w1, const float* __restrict__ wc,
                         const float* __restrict__ w2, const float* __restrict__ w3,
                         const float* __restrict__ w4,
                         _Float16* __restrict__ pw1, _Float16* __restrict__ pw2,
                         _Float16* __restrict__ pw3, _Float16* __restrict__ pw4)
{
  int idx = (int)blockIdx.x * 256 + (int)threadIdx.x;

  if (idx < 102400) {
    // W1e: conv folded into first-layer weight. K padded 784->800.
    // L1 packing: NTC=8, KSC=5, KCH=5, NC=1
    const int e    = idx & 7;
    const int lane = (idx >> 3) & 63;
    int t = idx >> 9;
    const int nt  = t & 7;     // NTC=8
    const int ksg = t >> 3;    // global kstep 0..24 (kc*5+ks_in)
    const int n = nt * 16 + (lane & 15);
    const int k = ksg * 32 + ((lane >> 4) << 3) + e;
    float val = 0.0f;
    if (k < 784) {
      const int pr = k / 28, pc = k % 28;
      #pragma unroll
      for (int i = 0; i < 3; ++i) {
        #pragma unroll
        for (int j = 0; j < 3; ++j) {
          const int orow = pr - i, ocol = pc - j;
          if (orow >= 0 && orow < 26 && ocol >= 0 && ocol < 26)
            val += wc[i * 3 + j] * w1[n * 676 + orow * 26 + ocol];
        }
      }
    }
    pw1[idx] = (_Float16)val;
    return;
  }
  idx -= 102400;
  if (idx < 65536)  { pack_one(w2, pw2, idx, 512, 128, 8, 4, 1); return; }
  idx -= 65536;
  if (idx < 131072) { pack_one(w3, pw3, idx, 256, 512, 4, 8, 2); return; }
  idx -= 131072;
  if (idx < 4096)   { pack_one(w4, pw4, idx, 10, 256, 1, 8, 1); return; }
}

// ---------------------------------------------------------------------------
// Templated GEMM: out[m,n] = act( A[m,:] . Bpk[:,n] + bias[n] )
// 512 threads = 8 waves, BM=128 rows/block, one 16-row m-tile per wave.
// B streamed through LDS in fragment-packed chunks via global_load_lds.
// ---------------------------------------------------------------------------

template<int KS_TOT, int KSC, int NT_TOT, int NTC, int KCH, int NC,
         bool A_FP32, bool RELU, bool OUT_F16, int N_REAL, int K_A>
__global__ __launch_bounds__(512)
void gemm_k(const void* __restrict__ Aptr, const _Float16* __restrict__ Bpk,
            const float* __restrict__ bias, void* __restrict__ Out)
{
  constexpr int CHUNK_BYTES = KSC * NTC * 64 * 16;
  constexpr int ROUNDS = CHUNK_BYTES / 8192;
  __shared__ char lds[CHUNK_BYTES];

  const int tid  = (int)threadIdx.x;
  const int lane = tid & 63;
  const int wid  = tid >> 6;
  const int ln   = lane & 15;
  const int hi   = lane >> 4;
  const int rowBase = (int)blockIdx.x * 128 + wid * 16;
  const int row0 = rowBase + hi * 4;

  auto loadA = [&](int ks) -> half8 {
    half8 h;
    if constexpr (A_FP32) {
      const int k0 = ks * 32 + hi * 8;
      if (k0 < K_A) {  // K_A=784: k0<=776 -> full 8 in-bounds; else zero-pad
        const float* ap = (const float*)Aptr + (size_t)(rowBase + ln) * K_A + k0;
        const f32x4 v0 = *(const f32x4*)ap;
        const f32x4 v1 = *(const f32x4*)(ap + 4);
        #pragma unroll
        for (int e = 0; e < 4; ++e) { h[e] = (_Float16)v0[e]; h[4 + e] = (_Float16)v1[e]; }
      } else {
        #pragma unroll
        for (int e = 0; e < 8; ++e) h[e] = (_Float16)0.0f;
      }
    } else {
      const _Float16* ap = (const _Float16*)Aptr + (size_t)(rowBase + ln) * K_A
                           + ks * 32 + hi * 8;
      h = *(const half8*)ap;
    }
    return h;
  };

  half8 afrag[(NC > 1) ? KS_TOT : 1];

  for (int nc = 0; nc < NC; ++nc) {
    f32x4 acc[NTC];
    #pragma unroll
    for (int nt = 0; nt < NTC; ++nt) {
      const int n_g = (nc * NTC + nt) * 16 + ln;
      const float bv = (n_g < N_REAL) ? bias[n_g] : 0.0f;
      f32x4 a = {bv, bv, bv, bv};
      acc[nt] = a;
    }

    #pragma unroll
    for (int kc = 0; kc < KCH; ++kc) {
      const char* csrc = (const char*)Bpk + (size_t)(nc * KCH + kc) * CHUNK_BYTES;
      #pragma unroll
      for (int r = 0; r < ROUNDS; ++r) {
        async_cp16(csrc + (size_t)(r * 8192 + tid * 16),
                   lds + r * 8192 + wid * 1024);
      }
      __syncthreads();

      #pragma unroll
      for (int ks = 0; ks < KSC; ++ks) {
        const int gks = kc * KSC + ks;
        half8 a;
        if constexpr (NC > 1) {
          if (nc == 0) { a = loadA(gks); afrag[gks] = a; }
          else         { a = afrag[gks]; }
        } else {
          a = loadA(gks);
        }
        #pragma unroll
        for (int nt = 0; nt < NTC; ++nt) {
          const half8 b = *(const half8*)(lds + ((size_t)(ks * NTC + nt) * 64 + lane) * 16);
          acc[nt] = __builtin_amdgcn_mfma_f32_16x16x32_f16(a, b, acc[nt], 0, 0, 0);
        }
      }
      __syncthreads();
    }

    #pragma unroll
    for (int nt = 0; nt < NTC; ++nt) {
      const int n_g = (nc * NTC + nt) * 16 + ln;
      #pragma unroll
      for (int r = 0; r < 4; ++r) {
        float v = acc[nt][r];
        if constexpr (RELU) v = v > 0.0f ? v : 0.0f;
        if constexpr (OUT_F16) {
          ((_Float16*)Out)[(size_t)(row0 + r) * (NT_TOT * 16) + n_g] = (_Float16)v;
        } else {
          if (n_g < N_REAL)
            ((float*)Out)[(size_t)(row0 + r) * N_REAL + n_g] = v;
        }
      }
    }
  }
}

// ---------------------------------------------------------------------------

extern "C" void kernel_launch(void* const* d_in, const int* in_sizes, int n_in,
                              void* d_out, int out_size, void* d_ws, size_t ws_size,
                              hipStream_t stream)
{
  const float* x     = (const float*)d_in[0];
  const float* wconv = (const float*)d_in[1];
  const float* w1    = (const float*)d_in[2];
  const float* b1    = (const float*)d_in[3];
  const float* w2    = (const float*)d_in[4];
  const float* b2    = (const float*)d_in[5];
  const float* w3    = (const float*)d_in[6];
  const float* b3    = (const float*)d_in[7];
  const float* w4    = (const float*)d_in[8];
  const float* b4    = (const float*)d_in[9];
  float* out = (float*)d_out;
  char*  ws  = (char*)d_ws;

  _Float16* pw1 = (_Float16*)(ws + 0);                         // 800*128*2  = 204800
  _Float16* pw2 = (_Float16*)(ws + 204800);                    // 128*512*2  = 131072
  _Float16* pw3 = (_Float16*)(ws + 335872);                    // 512*256*2  = 262144
  _Float16* pw4 = (_Float16*)(ws + 598016);                    // 256*16*2   = 8192
  _Float16* h1  = (_Float16*)(ws + 606208);                    // 65536*128*2
  _Float16* h2  = (_Float16*)(ws + 606208 + 16777216);         // 65536*512*2
  _Float16* h3  = (_Float16*)(ws + 606208 + 16777216 + 67108864); // 65536*256*2

  // pack all weights (conv folded into W1e) : 303104 elements
  pack_all<<<1184, 256, 0, stream>>>(w1, wconv, w2, w3, w4, pw1, pw2, pw3, pw4);

  // L1: [B,784]f32 x W1e[800,128] -> h1 [B,128]f16   (K padded to 800)
  gemm_k<25, 5,  8, 8, 5, 1, true,  true,  true, 128, 784>
      <<<512, 512, 0, stream>>>(x,  pw1, b1, h1);
  // L2: h1 x W2[128,512] -> h2 [B,512]f16
  gemm_k< 4, 4, 32, 8, 1, 4, false, true,  true, 512, 128>
      <<<512, 512, 0, stream>>>(h1, pw2, b2, h2);
  // L3: h2 x W3[512,256] -> h3 [B,256]f16
  gemm_k<16, 8, 16, 4, 2, 4, false, true,  true, 256, 512>
      <<<512, 512, 0, stream>>>(h2, pw3, b3, h3);
  // L4: h3 x W4[256,16] -> out [B,10]f32  (N padded to 16)
  gemm_k< 8, 8,  1, 1, 1, 1, false, false, false, 10, 256>
      <<<512, 512, 0, stream>>>(h3, pw4, b4, out);
}

// Round 2
// 340.776 us; speedup vs baseline: 1.0825x; 1.0825x over previous
//
#include <hip/hip_runtime.h>
#include <stdint.h>

typedef _Float16 half8 __attribute__((ext_vector_type(8)));
typedef float    f32x4 __attribute__((ext_vector_type(4)));

static __device__ __forceinline__ void async_cp16(const void* g, void* l) {
  __builtin_amdgcn_global_load_lds(
      (const __attribute__((address_space(1))) uint32_t*)g,
      (__attribute__((address_space(3))) uint32_t*)l,
      16, 0, 0);
}

// ---------------------------------------------------------------------------
// Weight packing into MFMA-fragment order, chunked to match the fused kernel's
// staging stream. Fragment f holds B for one (kstep, ntile): offset
// ((f*64+lane)*8) f16 elems; lane: n=(lane&15), k-sub=(lane>>4)*8+e.
// L1: K=784 padded->896 (28 ksteps), conv folded in. 7 chunks x (4ks x 8nt).
// L2: 4 chunks (g) x (4ks x 8nt), n = g*128+...
// L3: 8 chunks c=(kg,nh): ks=(c>>1)*4+ks_in, n=((c&1)*8+nt)*16+...
// L4: 1 chunk (8ks x 1nt), n<10 padded to 16.
// ---------------------------------------------------------------------------
__global__ void pack_all(const float* __restrict__ w1, const float* __restrict__ wc,
                         const float* __restrict__ w2, const float* __restrict__ w3,
                         const float* __restrict__ w4,
                         _Float16* __restrict__ pw1, _Float16* __restrict__ pw2,
                         _Float16* __restrict__ pw3, _Float16* __restrict__ pw4)
{
  int idx = (int)blockIdx.x * 256 + (int)threadIdx.x;

  if (idx < 114688) {           // L1: 28 ks x 8 nt fragments
    const int e = idx & 7, lane = (idx >> 3) & 63, f = idx >> 9;
    const int nt = f & 7, gks = f >> 3;
    const int n = nt * 16 + (lane & 15);
    const int k = gks * 32 + ((lane >> 4) << 3) + e;
    float val = 0.0f;
    if (k < 784) {
      const int pr = k / 28, pc = k % 28;
      #pragma unroll
      for (int i = 0; i < 3; ++i)
        #pragma unroll
        for (int j = 0; j < 3; ++j) {
          const int orow = pr - i, ocol = pc - j;
          if (orow >= 0 && orow < 26 && ocol >= 0 && ocol < 26)
            val += wc[i * 3 + j] * w1[n * 676 + orow * 26 + ocol];
        }
    }
    pw1[idx] = (_Float16)val;
    return;
  }
  idx -= 114688;
  if (idx < 65536) {            // L2
    const int e = idx & 7, lane = (idx >> 3) & 63, f = idx >> 9;
    const int nt = f & 7, ks = (f >> 3) & 3, g = f >> 5;
    const int n = g * 128 + nt * 16 + (lane & 15);
    const int k = ks * 32 + ((lane >> 4) << 3) + e;
    pw2[idx] = (_Float16)w2[n * 128 + k];
    return;
  }
  idx -= 65536;
  if (idx < 131072) {           // L3
    const int e = idx & 7, lane = (idx >> 3) & 63, f = idx >> 9;
    const int nt = f & 7, ks = (f >> 3) & 3, c = f >> 5;
    const int n = ((c & 1) * 8 + nt) * 16 + (lane & 15);
    const int k = ((c >> 1) * 4 + ks) * 32 + ((lane >> 4) << 3) + e;
    pw3[idx] = (_Float16)w3[n * 512 + k];
    return;
  }
  idx -= 131072;
  if (idx < 4096) {             // L4
    const int e = idx & 7, lane = (idx >> 3) & 63, f = idx >> 9;
    const int n = lane & 15;
    const int k = f * 32 + ((lane >> 4) << 3) + e;
    pw4[idx] = (_Float16)((n < 10) ? w4[n * 256 + k] : 0.0f);
    return;
  }
}

// ---------------------------------------------------------------------------
// Fused 4-layer MLP. 512 thr = 8 waves, 128 rows/block (16 rows/wave),
// grid 512. 20 staged weight chunks, 2-phase double-buffered LDS pipeline.
// Layer transitions: per-wave XOR-swizzled LDS transpose buffer (C-frag ->
// A-frag). Layer-3 accumulates over h2 in 128-col register chunks.
// ---------------------------------------------------------------------------
__global__ __launch_bounds__(512, 2)
void fused_mlp(const float* __restrict__ x,
               const _Float16* __restrict__ pw1, const _Float16* __restrict__ pw2,
               const _Float16* __restrict__ pw3, const _Float16* __restrict__ pw4,
               const float* __restrict__ b1, const float* __restrict__ b2,
               const float* __restrict__ b3, const float* __restrict__ b4,
               float* __restrict__ out)
{
  __shared__ char wbuf[2][32768];
  __shared__ char tbuf[8][8192];   // per-wave [16 rows][512 B], XOR-swizzled

  const int tid  = (int)threadIdx.x;
  const int lane = tid & 63;
  const int wid  = tid >> 6;
  const int ln   = lane & 15;
  const int hi   = lane >> 4;
  const int rowBase = (int)blockIdx.x * 128 + wid * 16;
  char* tb = tbuf[wid];

  auto stage = [&](int p) {
    const char* src; int nb;
    if (p < 7)       { src = (const char*)pw1 + (size_t)p * 32768; nb = 32768; }
    else if (p < 19) {
      const int j = p - 7, g = j / 3, r = j - g * 3;
      if (r == 0)      src = (const char*)pw2 + (size_t)g * 32768;
      else if (r == 1) src = (const char*)pw3 + (size_t)(2 * g) * 32768;
      else             src = (const char*)pw3 + (size_t)(2 * g + 1) * 32768;
      nb = 32768;
    } else           { src = (const char*)pw4; nb = 8192; }
    char* dst = wbuf[p & 1];
    const int rounds = nb >> 13;
    for (int r = 0; r < rounds; ++r)
      async_cp16(src + r * 8192 + tid * 16, dst + r * 8192 + wid * 1024);
  };

  auto Bfrag = [&](const char* buf, int f) -> half8 {
    return *(const half8*)(buf + (((f << 6) + lane) << 4));
  };
  auto twrite = [&](int row, int col, float v) {
    const int off = (row << 9) + ((col << 1) ^ ((row & 7) << 4));
    *(_Float16*)(tb + off) = (_Float16)v;
  };
  auto tread = [&](int ks) -> half8 {
    const int off = (ln << 9) + (((ks << 6) + (hi << 4)) ^ ((ln & 7) << 4));
    return *(const half8*)(tb + off);
  };

  const float* xrow = x + (size_t)(rowBase + ln) * 784;
  auto loadA = [&](int gks) -> half8 {
    half8 h;
    const int k0 = gks * 32 + hi * 8;
    if (k0 < 784) {
      const f32x4 v0 = *(const f32x4*)(xrow + k0);
      const f32x4 v1 = *(const f32x4*)(xrow + k0 + 4);
      #pragma unroll
      for (int e = 0; e < 4; ++e) { h[e] = (_Float16)v0[e]; h[4 + e] = (_Float16)v1[e]; }
    } else {
      #pragma unroll
      for (int e = 0; e < 8; ++e) h[e] = (_Float16)0.0f;
    }
    return h;
  };

  f32x4 acc1[8], acc3[16];
  #pragma unroll
  for (int nt = 0; nt < 8; ++nt) {
    const float bv = b1[nt * 16 + ln];
    f32x4 a = {bv, bv, bv, bv}; acc1[nt] = a;
  }
  #pragma unroll
  for (int q = 0; q < 16; ++q) {
    const float bv = b3[q * 16 + ln];
    f32x4 a = {bv, bv, bv, bv}; acc3[q] = a;
  }

  stage(0);
  __syncthreads();

  // ---- Layer 1: 7 phases over K=896 (784 real) ----
  #pragma unroll
  for (int kc = 0; kc < 7; ++kc) {
    stage(kc + 1);
    const char* bw = wbuf[kc & 1];
    half8 a[4];
    #pragma unroll
    for (int ks = 0; ks < 4; ++ks) a[ks] = loadA(kc * 4 + ks);
    #pragma unroll
    for (int ks = 0; ks < 4; ++ks)
      #pragma unroll
      for (int nt = 0; nt < 8; ++nt)
        acc1[nt] = __builtin_amdgcn_mfma_f32_16x16x32_f16(
            a[ks], Bfrag(bw, ks * 8 + nt), acc1[nt], 0, 0, 0);
    __syncthreads();
  }

  // h1 -> A-fragments via LDS transpose
  half8 a1h[4];
  #pragma unroll
  for (int nt = 0; nt < 8; ++nt)
    #pragma unroll
    for (int r = 0; r < 4; ++r)
      twrite(hi * 4 + r, nt * 16 + ln, fmaxf(acc1[nt][r], 0.0f));
  #pragma unroll
  for (int ks = 0; ks < 4; ++ks) a1h[ks] = tread(ks);

  // ---- Layers 2+3 interleaved: per 128-col chunk g of h2 ----
  #pragma unroll
  for (int g = 0; g < 4; ++g) {
    const int p = 7 + 3 * g;
    half8 a2c[4];

    // L2 chunk g
    stage(p + 1);
    {
      const char* bw = wbuf[p & 1];
      f32x4 acc2[8];
      #pragma unroll
      for (int nt = 0; nt < 8; ++nt) {
        const float bv = b2[g * 128 + nt * 16 + ln];
        f32x4 a = {bv, bv, bv, bv}; acc2[nt] = a;
      }
      #pragma unroll
      for (int ks = 0; ks < 4; ++ks)
        #pragma unroll
        for (int nt = 0; nt < 8; ++nt)
          acc2[nt] = __builtin_amdgcn_mfma_f32_16x16x32_f16(
              a1h[ks], Bfrag(bw, ks * 8 + nt), acc2[nt], 0, 0, 0);
      #pragma unroll
      for (int nt = 0; nt < 8; ++nt)
        #pragma unroll
        for (int r = 0; r < 4; ++r)
          twrite(hi * 4 + r, nt * 16 + ln, fmaxf(acc2[nt][r], 0.0f));
      #pragma unroll
      for (int ks = 0; ks < 4; ++ks) a2c[ks] = tread(ks);
    }
    __syncthreads();

    // L3, n-half 0
    stage(p + 2);
    {
      const char* bw = wbuf[(p + 1) & 1];
      #pragma unroll
      for (int ks = 0; ks < 4; ++ks)
        #pragma unroll
        for (int nt = 0; nt < 8; ++nt)
          acc3[nt] = __builtin_amdgcn_mfma_f32_16x16x32_f16(
              a2c[ks], Bfrag(bw, ks * 8 + nt), acc3[nt], 0, 0, 0);
    }
    __syncthreads();

    // L3, n-half 1
    stage(p + 3);
    {
      const char* bw = wbuf[p & 1];
      #pragma unroll
      for (int ks = 0; ks < 4; ++ks)
        #pragma unroll
        for (int nt = 0; nt < 8; ++nt)
          acc3[8 + nt] = __builtin_amdgcn_mfma_f32_16x16x32_f16(
              a2c[ks], Bfrag(bw, ks * 8 + nt), acc3[8 + nt], 0, 0, 0);
    }
    __syncthreads();
  }

  // ---- Layer 4 (phase 19, buf[1]) ----
  {
    #pragma unroll
    for (int q = 0; q < 16; ++q)
      #pragma unroll
      for (int r = 0; r < 4; ++r)
        twrite(hi * 4 + r, q * 16 + ln, fmaxf(acc3[q][r], 0.0f));
    half8 a3h[8];
    #pragma unroll
    for (int ks = 0; ks < 8; ++ks) a3h[ks] = tread(ks);

    const float bv = (ln < 10) ? b4[ln] : 0.0f;
    f32x4 acc4 = {bv, bv, bv, bv};
    const char* bw = wbuf[1];
    #pragma unroll
    for (int ks = 0; ks < 8; ++ks)
      acc4 = __builtin_amdgcn_mfma_f32_16x16x32_f16(
          a3h[ks], Bfrag(bw, ks), acc4, 0, 0, 0);

    if (ln < 10) {
      #pragma unroll
      for (int r = 0; r < 4; ++r)
        out[(size_t)(rowBase + hi * 4 + r) * 10 + ln] = acc4[r];
    }
  }
}

// ---------------------------------------------------------------------------

extern "C" void kernel_launch(void* const* d_in, const int* in_sizes, int n_in,
                              void* d_out, int out_size, void* d_ws, size_t ws_size,
                              hipStream_t stream)
{
  const float* x     = (const float*)d_in[0];
  const float* wconv = (const float*)d_in[1];
  const float* w1    = (const float*)d_in[2];
  const float* b1    = (const float*)d_in[3];
  const float* w2    = (const float*)d_in[4];
  const float* b2    = (const float*)d_in[5];
  const float* w3    = (const float*)d_in[6];
  const float* b3    = (const float*)d_in[7];
  const float* w4    = (const float*)d_in[8];
  const float* b4    = (const float*)d_in[9];
  float* out = (float*)d_out;
  char*  ws  = (char*)d_ws;

  _Float16* pw1 = (_Float16*)(ws + 0);        // 114688 f16 = 229376 B
  _Float16* pw2 = (_Float16*)(ws + 229376);   //  65536 f16 = 131072 B
  _Float16* pw3 = (_Float16*)(ws + 360448);   // 131072 f16 = 262144 B
  _Float16* pw4 = (_Float16*)(ws + 622592);   //   4096 f16 =   8192 B

  pack_all<<<1232, 256, 0, stream>>>(w1, wconv, w2, w3, w4, pw1, pw2, pw3, pw4);
  fused_mlp<<<512, 512, 0, stream>>>(x, pw1, pw2, pw3, pw4, b1, b2, b3, b4, out);
}